// Round 4
// baseline (389.297 us; speedup 1.0000x reference)
//
#include <hip/hip_runtime.h>
#include <hip/hip_bf16.h>
#include <stdint.h>

#define Mdim 8192
#define KSTEPS 256        // 8192 / 32
#define NWAVES 8
#define KSTEPS_W (KSTEPS / NWAVES)   // 32 k-steps per wave
#define PF 4              // prefetch depth (k-steps)

typedef __attribute__((ext_vector_type(8))) short short8v;  // 8 bf16 (4 VGPRs)
typedef __attribute__((ext_vector_type(4))) float f32x4;

// f32 -> bf16 via standard cast; compiler emits v_cvt_pk_bf16_f32 pairs (m240)
static __device__ __forceinline__ short bf16c(float f) {
  __hip_bfloat16 h = __float2bfloat16(f);
  union { __hip_bfloat16 h; short s; } c; c.h = h;
  return c.s;
}

// Repack x (f32 [8192][32]) into MFMA B-fragment layout:
// Bp[((ks*2 + h)*64 + lane)*8 + j] = bf16( B[ks*32 + (lane>>4)*8 + j][h*16 + (lane&15)] )
__global__ __launch_bounds__(256)
void repack_x(const float* __restrict__ x, short* __restrict__ Bp)
{
  int t = blockIdx.x * 256 + threadIdx.x;       // 32768 threads total
  int l = t & 63, h = (t >> 6) & 1, ks = t >> 7;
  int col = h * 16 + (l & 15);
  int kbase = ks * 32 + ((l >> 4) << 3);
  short8v v;
#pragma unroll
  for (int j = 0; j < 8; ++j) v[j] = bf16c(x[(size_t)(kbase + j) * 32 + col]);
  reinterpret_cast<short8v*>(Bp)[t] = v;
}

// Hot body for one chain. Typed __restrict__ params so clang emits scoped
// noalias metadata — the WRITE_AB stores must NOT serialize the A/B loads.
// 4-deep register double-buffer: 16 loads (~256 B/lane) in flight per wave.
template<int ABF16, int WRITE_AB, int HASPREV>
__device__ __forceinline__ void gemm_body(
    const float* __restrict__ Af, const short* __restrict__ As,
    short* __restrict__ AbOut, const short8v* __restrict__ Bp,
    const float* __restrict__ Tprev, float* __restrict__ Tout,
    short* __restrict__ BpOut, int r0)
{
  const int lane = threadIdx.x & 63;
  const int wid  = threadIdx.x >> 6;         // wave id 0..7 -> K chunk
  const int arow = r0 + (lane & 15);         // A-frag: row = lane%16
  const int koff = (lane >> 4) << 3;         // A-frag: k   = (lane/16)*8 + j
  const int ksbase = wid * KSTEPS_W;         // this wave's first k-step

  f32x4 acc0 = {0.f, 0.f, 0.f, 0.f};        // cols 0..15
  f32x4 acc1 = {0.f, 0.f, 0.f, 0.f};        // cols 16..31

  const short8v* bpB = Bp + (size_t)(ksbase << 1) * 64 + lane;  // +128/k-step
  short8v b[PF][2];

  if constexpr (ABF16 == 0) {
    const float* apB = Af + (size_t)arow * Mdim + ksbase * 32 + koff;
    short* abp = nullptr;
    if constexpr (WRITE_AB) abp = AbOut + (size_t)arow * Mdim + ksbase * 32 + koff;
    f32x4 a[PF][2];
#pragma unroll
    for (int j = 0; j < PF; ++j) {           // preload PF k-steps
      a[j][0] = *reinterpret_cast<const f32x4*>(apB + j * 32);
      a[j][1] = *reinterpret_cast<const f32x4*>(apB + j * 32 + 4);
      b[j][0] = bpB[(j * 2) * 64];
      b[j][1] = bpB[(j * 2 + 1) * 64];
    }
    const float*   apC = apB + PF * 32;      // prefetch cursors
    const short8v* bpC = bpB + PF * 128;
    for (int kg = 0; kg < KSTEPS_W / PF; ++kg) {
      const bool ok = (kg < KSTEPS_W / PF - 1);   // uniform: wrap on last group
#pragma unroll
      for (int j = 0; j < PF; ++j) {
        short8v av;
#pragma unroll
        for (int q = 0; q < 4; ++q) av[q] = bf16c(a[j][0][q]);
#pragma unroll
        for (int q = 0; q < 4; ++q) av[4 + q] = bf16c(a[j][1][q]);
        acc0 = __builtin_amdgcn_mfma_f32_16x16x32_bf16(av, b[j][0], acc0, 0, 0, 0);
        acc1 = __builtin_amdgcn_mfma_f32_16x16x32_bf16(av, b[j][1], acc1, 0, 0, 0);
        if constexpr (WRITE_AB) {
          *reinterpret_cast<short8v*>(abp) = av;
          abp += 32;
        }
        // prefetch k-step (kg*PF + j + PF); wrap to base on last group (data unused)
        const float*   pa = ok ? apC : apB;
        const short8v* pb = ok ? bpC : bpB;
        a[j][0] = *reinterpret_cast<const f32x4*>(pa);
        a[j][1] = *reinterpret_cast<const f32x4*>(pa + 4);
        b[j][0] = pb[0];
        b[j][1] = pb[64];
        apC += 32; bpC += 128;
      }
    }
  } else {
    const short* apB = As + (size_t)arow * Mdim + ksbase * 32 + koff;
    short8v a[PF];
#pragma unroll
    for (int j = 0; j < PF; ++j) {
      a[j]    = *reinterpret_cast<const short8v*>(apB + j * 32);
      b[j][0] = bpB[(j * 2) * 64];
      b[j][1] = bpB[(j * 2 + 1) * 64];
    }
    const short*   apC = apB + PF * 32;
    const short8v* bpC = bpB + PF * 128;
    for (int kg = 0; kg < KSTEPS_W / PF; ++kg) {
      const bool ok = (kg < KSTEPS_W / PF - 1);
#pragma unroll
      for (int j = 0; j < PF; ++j) {
        acc0 = __builtin_amdgcn_mfma_f32_16x16x32_bf16(a[j], b[j][0], acc0, 0, 0, 0);
        acc1 = __builtin_amdgcn_mfma_f32_16x16x32_bf16(a[j], b[j][1], acc1, 0, 0, 0);
        const short*   pa = ok ? apC : apB;
        const short8v* pb = ok ? bpC : bpB;
        a[j]    = *reinterpret_cast<const short8v*>(pa);
        b[j][0] = pb[0];
        b[j][1] = pb[64];
        apC += 32; bpC += 128;
      }
    }
  }

  // ---- per-wave partials -> LDS ----
  // C/D layout: col = lane&15, row = (lane>>4)*4 + reg  (m89-verified)
  __shared__ float Cl[NWAVES][16][32];   // 16 KB partials
  __shared__ float Cred[16][32];         // 2 KB reduced tile
  {
    const int crow = (lane >> 4) << 2;
    const int ccol = lane & 15;
#pragma unroll
    for (int q = 0; q < 4; ++q) {
      Cl[wid][crow + q][ccol] = acc0[q];
      Cl[wid][crow + q][16 + ccol] = acc1[q];
    }
  }
  __syncthreads();

  // ---- reduce 8 partials + Chebyshev recurrence + Tout write ----
  {
    const int t = threadIdx.x;
    const int row = t >> 5, col = t & 31;
    float v = Cl[0][row][col] + Cl[1][row][col] + Cl[2][row][col] + Cl[3][row][col]
            + Cl[4][row][col] + Cl[5][row][col] + Cl[6][row][col] + Cl[7][row][col];
    if constexpr (HASPREV) {
      v = 2.f * v - Tprev[(size_t)r0 * 32 + t];
    }
    Tout[(size_t)r0 * 32 + t] = v;
    Cred[row][col] = v;
  }
  __syncthreads();

  // ---- BpOut fragment write: 64 short8v entries for this 16-row tile ----
  if (threadIdx.x < 64) {
    const int t = threadIdx.x;
    const int ksOut = r0 >> 5;
    const int sub = (r0 >> 4) & 1;          // which half of the 32-row group
    const int h = t >> 5;                   // column half 0/1
    const int lp = (t & 31) + sub * 32;     // fragment lane we produce
    const int col = h * 16 + (lp & 15);
    const int lrbase = (lp & 16) ? 8 : 0;   // local row base within our 16 rows
    short8v v;
#pragma unroll
    for (int j = 0; j < 8; ++j) v[j] = bf16c(Cred[lrbase + j][col]);
    reinterpret_cast<short8v*>(BpOut)[(ksOut << 1 | h) * 64 + lp] = v;
  }
}

// Fused stage for BOTH chains: blocks 0..511 -> chain l, 512..1023 -> chain u.
template<int ABF16, int WRITE_AB, int HASPREV>
__global__ __launch_bounds__(512)
void gemm_stage(const float* __restrict__ AfL, const float* __restrict__ AfU,
                const short* __restrict__ AsL, const short* __restrict__ AsU,
                short* __restrict__ AbOutL, short* __restrict__ AbOutU,
                const short8v* __restrict__ BpL, const short8v* __restrict__ BpU,
                const float* __restrict__ TprevL, const float* __restrict__ TprevU,
                float* __restrict__ ToutL, float* __restrict__ ToutU,
                short* __restrict__ BpOutL, short* __restrict__ BpOutU)
{
  const int r0 = (blockIdx.x & 511) << 4;
  if (blockIdx.x < 512) {
    gemm_body<ABF16, WRITE_AB, HASPREV>(AfL, AsL, AbOutL, BpL, TprevL, ToutL, BpOutL, r0);
  } else {
    gemm_body<ABF16, WRITE_AB, HASPREV>(AfU, AsU, AbOutU, BpU, TprevU, ToutU, BpOutU, r0);
  }
}

// y[n][o] = sum_k sum_i Xk[n][i] * W[i][o][k],  W: [32][32][7] f32
__global__ __launch_bounds__(256)
void combine(const float* __restrict__ x,
             const float* __restrict__ T1l, const float* __restrict__ T2l,
             const float* __restrict__ T3l, const float* __restrict__ T1u,
             const float* __restrict__ T2u, const float* __restrict__ T3u,
             const float* __restrict__ W, float* __restrict__ y)
{
  __shared__ float Wl[7168];
  for (int i = threadIdx.x; i < 7168; i += 256) Wl[i] = W[i];
  __syncthreads();
  int t = blockIdx.x * 256 + threadIdx.x;
  int n = t >> 5, o = t & 31;
  const float* Xs[7] = {x, T1l, T2l, T3l, T1u, T2u, T3u};
  float sum = 0.f;
#pragma unroll
  for (int k = 0; k < 7; ++k) {
    const f32x4* Xr = reinterpret_cast<const f32x4*>(Xs[k] + (size_t)n * 32);
#pragma unroll
    for (int i4 = 0; i4 < 8; ++i4) {
      f32x4 xv = Xr[i4];
#pragma unroll
      for (int j = 0; j < 4; ++j)
        sum += xv[j] * Wl[(i4 * 4 + j) * 224 + o * 7 + k];
    }
  }
  y[t] = sum;
}

extern "C" void kernel_launch(void* const* d_in, const int* in_sizes, int n_in,
                              void* d_out, int out_size, void* d_ws, size_t ws_size,
                              hipStream_t stream)
{
  const float* x  = (const float*)d_in[0];
  const float* Ll = (const float*)d_in[1];
  const float* Lu = (const float*)d_in[2];
  const float* W  = (const float*)d_in[3];
  float* y = (float*)d_out;

  char* ws = (char*)d_ws;
  size_t off = 0;
  auto alloc = [&](size_t bytes) -> void* {
    void* p = ws + off; off += (bytes + 255) & ~(size_t)255; return p;
  };
  short* Bx  = (short*)alloc(512 * 1024);
  short* Bl1 = (short*)alloc(512 * 1024);
  short* Bl2 = (short*)alloc(512 * 1024);
  short* Bu1 = (short*)alloc(512 * 1024);
  short* Bu2 = (short*)alloc(512 * 1024);
  float* T1l = (float*)alloc(1u << 20);
  float* T2l = (float*)alloc(1u << 20);
  float* T3l = (float*)alloc(1u << 20);
  float* T1u = (float*)alloc(1u << 20);
  float* T2u = (float*)alloc(1u << 20);
  float* T3u = (float*)alloc(1u << 20);

  const size_t lbytes = (size_t)Mdim * Mdim * sizeof(short);
  bool useBF = (ws_size >= off + 2 * lbytes);
  short* Llb = nullptr; short* Lub = nullptr;
  if (useBF) { Llb = (short*)alloc(lbytes); Lub = (short*)alloc(lbytes); }

  repack_x<<<128, 256, 0, stream>>>(x, Bx);

  if (useBF) {
    // stage 1 converts L->bf16 on the fly and caches it; stages 2-3 read bf16
    gemm_stage<0,1,0><<<1024,512,0,stream>>>(Ll, Lu, nullptr, nullptr, Llb, Lub,
        (const short8v*)Bx, (const short8v*)Bx, nullptr, nullptr,
        T1l, T1u, Bl1, Bu1);
    gemm_stage<1,0,1><<<1024,512,0,stream>>>(nullptr, nullptr, Llb, Lub, nullptr, nullptr,
        (const short8v*)Bl1, (const short8v*)Bu1, x, x,
        T2l, T2u, Bl2, Bu2);
    gemm_stage<1,0,1><<<1024,512,0,stream>>>(nullptr, nullptr, Llb, Lub, nullptr, nullptr,
        (const short8v*)Bl2, (const short8v*)Bu2, T1l, T1u,
        T3l, T3u, Bl1, Bu1);
  } else {
    gemm_stage<0,0,0><<<1024,512,0,stream>>>(Ll, Lu, nullptr, nullptr, nullptr, nullptr,
        (const short8v*)Bx, (const short8v*)Bx, nullptr, nullptr,
        T1l, T1u, Bl1, Bu1);
    gemm_stage<0,0,1><<<1024,512,0,stream>>>(Ll, Lu, nullptr, nullptr, nullptr, nullptr,
        (const short8v*)Bl1, (const short8v*)Bu1, x, x,
        T2l, T2u, Bl2, Bu2);
    gemm_stage<0,0,1><<<1024,512,0,stream>>>(Ll, Lu, nullptr, nullptr, nullptr, nullptr,
        (const short8v*)Bl2, (const short8v*)Bu2, T1l, T1u,
        T3l, T3u, Bl1, Bu1);
  }

  combine<<<1024, 256, 0, stream>>>(x, T1l, T2l, T3l, T1u, T2u, T3u, W, y);
}

// Round 5
// 355.093 us; speedup vs baseline: 1.0963x; 1.0963x over previous
//
#include <hip/hip_runtime.h>
#include <hip/hip_bf16.h>
#include <stdint.h>

#define Mdim 8192
#define KSTEPS 256        // 8192 / 32
#define NWAVES 8
#define KSTEPS_W (KSTEPS / NWAVES)   // 32 k-steps per wave

typedef __attribute__((ext_vector_type(8))) short short8v;  // 8 bf16 (4 VGPRs)
typedef __attribute__((ext_vector_type(4))) float f32x4;

// f32 -> bf16 via standard cast; compiler emits v_cvt_pk_bf16_f32 pairs (m240)
static __device__ __forceinline__ short bf16c(float f) {
  __hip_bfloat16 h = __float2bfloat16(f);
  union { __hip_bfloat16 h; short s; } c; c.h = h;
  return c.s;
}

// Streaming f32 -> bf16 conversion. Nontemporal loads keep the 268 MB f32
// stream from thrashing L3, so the 134 MB bf16 output stays L3-resident for
// the GEMM stages that immediately follow.
__global__ __launch_bounds__(256)
void convert_bf16(const float* __restrict__ src, short* __restrict__ dst, int n8)
{
  const int stride = gridDim.x * 256;
  for (int i = blockIdx.x * 256 + threadIdx.x; i < n8; i += stride) {
    const f32x4* p = reinterpret_cast<const f32x4*>(src + (size_t)i * 8);
    f32x4 a0 = __builtin_nontemporal_load(p);
    f32x4 a1 = __builtin_nontemporal_load(p + 1);
    short8v v;
#pragma unroll
    for (int j = 0; j < 4; ++j) v[j] = bf16c(a0[j]);
#pragma unroll
    for (int j = 0; j < 4; ++j) v[4 + j] = bf16c(a1[j]);
    reinterpret_cast<short8v*>(dst)[i] = v;
  }
}

// Repack x (f32 [8192][32]) into MFMA B-fragment layout:
// Bp[((ks*2 + h)*64 + lane)*8 + j] = bf16( B[ks*32 + (lane>>4)*8 + j][h*16 + (lane&15)] )
__global__ __launch_bounds__(256)
void repack_x(const float* __restrict__ x, short* __restrict__ Bp)
{
  int t = blockIdx.x * 256 + threadIdx.x;       // 32768 threads total
  int l = t & 63, h = (t >> 6) & 1, ks = t >> 7;
  int col = h * 16 + (l & 15);
  int kbase = ks * 32 + ((l >> 4) << 3);
  short8v v;
#pragma unroll
  for (int j = 0; j < 8; ++j) v[j] = bf16c(x[(size_t)(kbase + j) * 32 + col]);
  reinterpret_cast<short8v*>(Bp)[t] = v;
}

// One Chebyshev GEMM stage, single chain.
// Tout = (A @ B)            (HASPREV=0)
// Tout = 2*(A @ B) - Tprev  (HASPREV=1)
// A: f32 (ABF16=0, fallback only) or bf16-as-short (ABF16=1), row-major.
// B: fragment-packed bf16. Emits BpOut (next stage's B input).
// Grid: 512 blocks x 512 threads (8 waves, K-split 8 x 1024, LDS reduction).
// Simple compiler-scheduled loop — round-3 structure (manual PF regressed:
// VGPR 68 > 64 halves occupancy, round 4).
template<int ABF16, int HASPREV>
__global__ __launch_bounds__(512)
void gemm_stage(const float* __restrict__ Af, const short* __restrict__ As,
                const short8v* __restrict__ Bp,
                const float* __restrict__ Tprev, float* __restrict__ Tout,
                short* __restrict__ BpOut)
{
  const int lane = threadIdx.x & 63;
  const int wid  = threadIdx.x >> 6;         // wave id 0..7 -> K chunk
  const int r0 = blockIdx.x << 4;            // first output row of this tile
  const int arow = r0 + (lane & 15);         // A-frag: row = lane%16
  const int koff = (lane >> 4) << 3;         // A-frag: k   = (lane/16)*8 + j
  const int ksbase = wid * KSTEPS_W;         // this wave's first k-step

  f32x4 acc0 = {0.f, 0.f, 0.f, 0.f};         // cols 0..15
  f32x4 acc1 = {0.f, 0.f, 0.f, 0.f};         // cols 16..31

  if constexpr (ABF16 == 0) {
    const float* ap = Af + (size_t)arow * Mdim + ksbase * 32 + koff;
#pragma unroll 8
    for (int ks = 0; ks < KSTEPS_W; ++ks) {
      const int g = ksbase + ks;
      f32x4 a0 = *reinterpret_cast<const f32x4*>(ap);
      f32x4 a1 = *reinterpret_cast<const f32x4*>(ap + 4);
      short8v av;
#pragma unroll
      for (int j = 0; j < 4; ++j) av[j] = bf16c(a0[j]);
#pragma unroll
      for (int j = 0; j < 4; ++j) av[4 + j] = bf16c(a1[j]);
      short8v b0 = Bp[(g << 1) * 64 + lane];
      short8v b1 = Bp[((g << 1) + 1) * 64 + lane];
      acc0 = __builtin_amdgcn_mfma_f32_16x16x32_bf16(av, b0, acc0, 0, 0, 0);
      acc1 = __builtin_amdgcn_mfma_f32_16x16x32_bf16(av, b1, acc1, 0, 0, 0);
      ap += 32;
    }
  } else {
    const short* ap = As + (size_t)arow * Mdim + ksbase * 32 + koff;
#pragma unroll 8
    for (int ks = 0; ks < KSTEPS_W; ++ks) {
      const int g = ksbase + ks;
      short8v av = *reinterpret_cast<const short8v*>(ap);
      short8v b0 = Bp[(g << 1) * 64 + lane];
      short8v b1 = Bp[((g << 1) + 1) * 64 + lane];
      acc0 = __builtin_amdgcn_mfma_f32_16x16x32_bf16(av, b0, acc0, 0, 0, 0);
      acc1 = __builtin_amdgcn_mfma_f32_16x16x32_bf16(av, b1, acc1, 0, 0, 0);
      ap += 32;
    }
  }

  // ---- per-wave partials -> LDS ----
  // C/D layout: col = lane&15, row = (lane>>4)*4 + reg  (m89-verified)
  __shared__ float Cl[NWAVES][16][32];   // 16 KB partials
  __shared__ float Cred[16][32];         // 2 KB reduced tile
  {
    const int crow = (lane >> 4) << 2;
    const int ccol = lane & 15;
#pragma unroll
    for (int q = 0; q < 4; ++q) {
      Cl[wid][crow + q][ccol] = acc0[q];
      Cl[wid][crow + q][16 + ccol] = acc1[q];
    }
  }
  __syncthreads();

  // ---- reduce 8 partials + Chebyshev recurrence + Tout write ----
  {
    const int t = threadIdx.x;
    const int row = t >> 5, col = t & 31;
    float v = Cl[0][row][col] + Cl[1][row][col] + Cl[2][row][col] + Cl[3][row][col]
            + Cl[4][row][col] + Cl[5][row][col] + Cl[6][row][col] + Cl[7][row][col];
    if constexpr (HASPREV) {
      v = 2.f * v - Tprev[(size_t)r0 * 32 + t];
    }
    Tout[(size_t)r0 * 32 + t] = v;
    Cred[row][col] = v;
  }
  __syncthreads();

  // ---- BpOut fragment write: 64 short8v entries for this 16-row tile ----
  if (threadIdx.x < 64) {
    const int t = threadIdx.x;
    const int ksOut = r0 >> 5;
    const int sub = (r0 >> 4) & 1;          // which half of the 32-row group
    const int h = t >> 5;                   // column half 0/1
    const int lp = (t & 31) + sub * 32;     // fragment lane we produce
    const int col = h * 16 + (lp & 15);
    const int lrbase = (lp & 16) ? 8 : 0;   // local row base within our 16 rows
    short8v v;
#pragma unroll
    for (int j = 0; j < 8; ++j) v[j] = bf16c(Cred[lrbase + j][col]);
    reinterpret_cast<short8v*>(BpOut)[(ksOut << 1 | h) * 64 + lp] = v;
  }
}

// y[n][o] = sum_k sum_i Xk[n][i] * W[i][o][k],  W: [32][32][7] f32
__global__ __launch_bounds__(256)
void combine(const float* __restrict__ x,
             const float* __restrict__ T1l, const float* __restrict__ T2l,
             const float* __restrict__ T3l, const float* __restrict__ T1u,
             const float* __restrict__ T2u, const float* __restrict__ T3u,
             const float* __restrict__ W, float* __restrict__ y)
{
  __shared__ float Wl[7168];
  for (int i = threadIdx.x; i < 7168; i += 256) Wl[i] = W[i];
  __syncthreads();
  int t = blockIdx.x * 256 + threadIdx.x;
  int n = t >> 5, o = t & 31;
  const float* Xs[7] = {x, T1l, T2l, T3l, T1u, T2u, T3u};
  float sum = 0.f;
#pragma unroll
  for (int k = 0; k < 7; ++k) {
    const f32x4* Xr = reinterpret_cast<const f32x4*>(Xs[k] + (size_t)n * 32);
#pragma unroll
    for (int i4 = 0; i4 < 8; ++i4) {
      f32x4 xv = Xr[i4];
#pragma unroll
      for (int j = 0; j < 4; ++j)
        sum += xv[j] * Wl[(i4 * 4 + j) * 224 + o * 7 + k];
    }
  }
  y[t] = sum;
}

extern "C" void kernel_launch(void* const* d_in, const int* in_sizes, int n_in,
                              void* d_out, int out_size, void* d_ws, size_t ws_size,
                              hipStream_t stream)
{
  const float* x  = (const float*)d_in[0];
  const float* Ll = (const float*)d_in[1];
  const float* Lu = (const float*)d_in[2];
  const float* W  = (const float*)d_in[3];
  float* y = (float*)d_out;

  char* ws = (char*)d_ws;
  size_t off = 0;
  auto alloc = [&](size_t bytes) -> void* {
    void* p = ws + off; off += (bytes + 255) & ~(size_t)255; return p;
  };
  short* Bx  = (short*)alloc(512 * 1024);
  short* Bp0 = (short*)alloc(512 * 1024);
  short* Bp1 = (short*)alloc(512 * 1024);
  float* T1l = (float*)alloc(1u << 20);
  float* T2l = (float*)alloc(1u << 20);
  float* T3l = (float*)alloc(1u << 20);
  float* T1u = (float*)alloc(1u << 20);
  float* T2u = (float*)alloc(1u << 20);
  float* T3u = (float*)alloc(1u << 20);

  const size_t lbytes = (size_t)Mdim * Mdim * sizeof(short);
  bool useBF = (ws_size >= off + 2 * lbytes);
  short* Llb = nullptr; short* Lub = nullptr;
  if (useBF) { Llb = (short*)alloc(lbytes); Lub = (short*)alloc(lbytes); }

  repack_x<<<128, 256, 0, stream>>>(x, Bx);

  const int n8 = Mdim * (Mdim / 8);   // 8,388,608 short8v groups per matrix

  if (useBF) {
    // Chain l: convert then 3 bf16 stages while Llb (134 MB) is L3-resident.
    convert_bf16<<<2048, 256, 0, stream>>>(Ll, Llb, n8);
    gemm_stage<1,0><<<512,512,0,stream>>>(nullptr, Llb, (const short8v*)Bx,  nullptr, T1l, Bp0);
    gemm_stage<1,1><<<512,512,0,stream>>>(nullptr, Llb, (const short8v*)Bp0, x,       T2l, Bp1);
    gemm_stage<1,1><<<512,512,0,stream>>>(nullptr, Llb, (const short8v*)Bp1, T1l,     T3l, Bp0);
    // Chain u
    convert_bf16<<<2048, 256, 0, stream>>>(Lu, Lub, n8);
    gemm_stage<1,0><<<512,512,0,stream>>>(nullptr, Lub, (const short8v*)Bx,  nullptr, T1u, Bp0);
    gemm_stage<1,1><<<512,512,0,stream>>>(nullptr, Lub, (const short8v*)Bp0, x,       T2u, Bp1);
    gemm_stage<1,1><<<512,512,0,stream>>>(nullptr, Lub, (const short8v*)Bp1, T1u,     T3u, Bp0);
  } else {
    // Fallback: f32 A straight from inputs (no workspace for bf16 copies)
    gemm_stage<0,0><<<512,512,0,stream>>>(Ll, nullptr, (const short8v*)Bx,  nullptr, T1l, Bp0);
    gemm_stage<0,1><<<512,512,0,stream>>>(Ll, nullptr, (const short8v*)Bp0, x,       T2l, Bp1);
    gemm_stage<0,1><<<512,512,0,stream>>>(Ll, nullptr, (const short8v*)Bp1, T1l,     T3l, Bp0);
    gemm_stage<0,0><<<512,512,0,stream>>>(Lu, nullptr, (const short8v*)Bx,  nullptr, T1u, Bp0);
    gemm_stage<0,1><<<512,512,0,stream>>>(Lu, nullptr, (const short8v*)Bp0, x,       T2u, Bp1);
    gemm_stage<0,1><<<512,512,0,stream>>>(Lu, nullptr, (const short8v*)Bp1, T1u,     T3u, Bp0);
  }

  combine<<<1024, 256, 0, stream>>>(x, T1l, T2l, T3l, T1u, T2u, T3u, W, y);
}

// Round 6
// 342.176 us; speedup vs baseline: 1.1377x; 1.0377x over previous
//
#include <hip/hip_runtime.h>
#include <hip/hip_bf16.h>
#include <stdint.h>

#define Mdim 8192
#define KSTEPS 256        // 8192 / 32
#define NWAVES 8
#define KSTEPS_W (KSTEPS / NWAVES)   // 32 k-steps per wave

typedef __attribute__((ext_vector_type(8))) short short8v;  // 8 bf16 (4 VGPRs)
typedef __attribute__((ext_vector_type(4))) float f32x4;

// f32 -> bf16 via standard cast; compiler emits v_cvt_pk_bf16_f32 pairs (m240)
static __device__ __forceinline__ short bf16c(float f) {
  __hip_bfloat16 h = __float2bfloat16(f);
  union { __hip_bfloat16 h; short s; } c; c.h = h;
  return c.s;
}

// async global->LDS DMA, 16 B/lane. LDS dest = uniform base + lane*16 (m104);
// global src is per-lane. Does not consume VGPRs for the data.
static __device__ __forceinline__ void gload_lds16(const void* g, void* l) {
  __builtin_amdgcn_global_load_lds(
      (const __attribute__((address_space(1))) void*)g,
      (__attribute__((address_space(3))) void*)l, 16, 0, 0);
}

// Streaming f32 -> bf16 conversion. Nontemporal loads keep the 268 MB f32
// stream from thrashing L3, so the 134 MB bf16 output stays L3-resident for
// the GEMM stages that immediately follow.
__global__ __launch_bounds__(256)
void convert_bf16(const float* __restrict__ src, short* __restrict__ dst, int n8)
{
  const int stride = gridDim.x * 256;
  for (int i = blockIdx.x * 256 + threadIdx.x; i < n8; i += stride) {
    const f32x4* p = reinterpret_cast<const f32x4*>(src + (size_t)i * 8);
    f32x4 a0 = __builtin_nontemporal_load(p);
    f32x4 a1 = __builtin_nontemporal_load(p + 1);
    short8v v;
#pragma unroll
    for (int j = 0; j < 4; ++j) v[j] = bf16c(a0[j]);
#pragma unroll
    for (int j = 0; j < 4; ++j) v[4 + j] = bf16c(a1[j]);
    reinterpret_cast<short8v*>(dst)[i] = v;
  }
}

// Repack x (f32 [8192][32]) into MFMA B-fragment layout:
// Bp[((ks*2 + h)*64 + lane)*8 + j] = bf16( B[ks*32 + (lane>>4)*8 + j][h*16 + (lane&15)] )
__global__ __launch_bounds__(256)
void repack_x(const float* __restrict__ x, short* __restrict__ Bp)
{
  int t = blockIdx.x * 256 + threadIdx.x;       // 32768 threads total
  int l = t & 63, h = (t >> 6) & 1, ks = t >> 7;
  int col = h * 16 + (l & 15);
  int kbase = ks * 32 + ((l >> 4) << 3);
  short8v v;
#pragma unroll
  for (int j = 0; j < 8; ++j) v[j] = bf16c(x[(size_t)(kbase + j) * 32 + col]);
  reinterpret_cast<short8v*>(Bp)[t] = v;
}

// bf16 Chebyshev GEMM stage with global_load_lds pipeline.
// Tout = (A @ B) [HASPREV=0]  or  2*(A @ B) - Tprev [HASPREV=1]
// A: bf16 row-major [8192][8192]. B: fragment-packed bf16.
// Block: 512 thr = 8 waves, 16-row tile, K-split 8 x 1024.
// Per wave per k-step: 3 LDS-DMA ops (A 1KB, B 2x1KB) into a private
// depth-2 ring; counted s_waitcnt vmcnt(3) (= 1 step of 3 ops in flight
// behind the one we consume). No barriers in the main loop (per-wave LDS).
// Per-lane global src is pre-arranged so LDS image == fragment layout:
// lane l reads its own 16 B at base + l*16 (sequential -> conflict-free).
template<int HASPREV>
__global__ __launch_bounds__(512)
void gemm_bf16_stage(const short* __restrict__ As, const short* __restrict__ Bps,
                     const float* __restrict__ Tprev, float* __restrict__ Tout,
                     short* __restrict__ BpOut)
{
  __shared__ __align__(16) short Asl[NWAVES][2][512];    // 16 KB
  __shared__ __align__(16) short Bsl[NWAVES][2][1024];   // 32 KB
  __shared__ float Cl[NWAVES][16][32];                   // 16 KB
  __shared__ float Cred[16][32];                         //  2 KB

  const int lane = threadIdx.x & 63;
  const int wid  = threadIdx.x >> 6;         // wave id 0..7 -> K chunk
  const int r0 = blockIdx.x << 4;            // first output row of this tile
  const int ksbase = wid * KSTEPS_W;         // this wave's first k-step

  // per-lane global sources (shorts)
  const short* aSrc = As + (size_t)(r0 + (lane & 15)) * Mdim
                         + ksbase * 32 + ((lane >> 4) << 3);
  const short* bSrc = Bps + (size_t)ksbase * 1024 + lane * 8;
  // step g: A += g*32 ; B += g*1024 (h=1 at +512)

  short* aD[2] = { &Asl[wid][0][0], &Asl[wid][1][0] };
  short* bD[2] = { &Bsl[wid][0][0], &Bsl[wid][1][0] };

#define ISSUE(g, slot)  {                                   \
    gload_lds16(aSrc + (g) * 32,          aD[slot]);        \
    gload_lds16(bSrc + (g) * 1024,        bD[slot]);        \
    gload_lds16(bSrc + (g) * 1024 + 512,  bD[slot] + 512); }

  f32x4 acc0 = {0.f, 0.f, 0.f, 0.f};        // cols 0..15
  f32x4 acc1 = {0.f, 0.f, 0.f, 0.f};        // cols 16..31

#define CONSUME(slot)  {                                                      \
    short8v av = *reinterpret_cast<const short8v*>(&Asl[wid][slot][lane * 8]);\
    short8v b0 = *reinterpret_cast<const short8v*>(&Bsl[wid][slot][lane * 8]);\
    short8v b1 = *reinterpret_cast<const short8v*>(&Bsl[wid][slot][512 + lane * 8]); \
    acc0 = __builtin_amdgcn_mfma_f32_16x16x32_bf16(av, b0, acc0, 0, 0, 0);    \
    acc1 = __builtin_amdgcn_mfma_f32_16x16x32_bf16(av, b1, acc1, 0, 0, 0); }

  ISSUE(0, 0);
  ISSUE(1, 1);
  for (int gg = 0; gg < 15; ++gg) {
    const int g = gg * 2;
    asm volatile("s_waitcnt vmcnt(3)" ::: "memory");
    CONSUME(0);
    ISSUE(g + 2, 0);
    asm volatile("s_waitcnt vmcnt(3)" ::: "memory");
    CONSUME(1);
    ISSUE(g + 3, 1);
  }
  asm volatile("s_waitcnt vmcnt(3)" ::: "memory");
  CONSUME(0);                               // step 30
  asm volatile("s_waitcnt vmcnt(0)" ::: "memory");
  CONSUME(1);                               // step 31
#undef ISSUE
#undef CONSUME

  // ---- per-wave partials -> LDS ----
  // C/D layout: col = lane&15, row = (lane>>4)*4 + reg  (m89-verified)
  {
    const int crow = (lane >> 4) << 2;
    const int ccol = lane & 15;
#pragma unroll
    for (int q = 0; q < 4; ++q) {
      Cl[wid][crow + q][ccol] = acc0[q];
      Cl[wid][crow + q][16 + ccol] = acc1[q];
    }
  }
  __syncthreads();

  // ---- reduce 8 partials + Chebyshev recurrence + Tout write ----
  {
    const int t = threadIdx.x;
    const int row = t >> 5, col = t & 31;
    float v = Cl[0][row][col] + Cl[1][row][col] + Cl[2][row][col] + Cl[3][row][col]
            + Cl[4][row][col] + Cl[5][row][col] + Cl[6][row][col] + Cl[7][row][col];
    if constexpr (HASPREV) {
      v = 2.f * v - Tprev[(size_t)r0 * 32 + t];
    }
    Tout[(size_t)r0 * 32 + t] = v;
    Cred[row][col] = v;
  }
  __syncthreads();

  // ---- BpOut fragment write: 64 short8v entries for this 16-row tile ----
  if (threadIdx.x < 64) {
    const int t = threadIdx.x;
    const int ksOut = r0 >> 5;
    const int sub = (r0 >> 4) & 1;          // which half of the 32-row group
    const int h = t >> 5;                   // column half 0/1
    const int lp = (t & 31) + sub * 32;     // fragment lane we produce
    const int col = h * 16 + (lp & 15);
    const int lrbase = (lp & 16) ? 8 : 0;   // local row base within our 16 rows
    short8v v;
#pragma unroll
    for (int j = 0; j < 8; ++j) v[j] = bf16c(Cred[lrbase + j][col]);
    reinterpret_cast<short8v*>(BpOut)[(ksOut << 1 | h) * 64 + lp] = v;
  }
}

// Fallback f32-A stage (only used if workspace lacks room for bf16 copies).
template<int HASPREV>
__global__ __launch_bounds__(512)
void gemm_f32_stage(const float* __restrict__ Af, const short8v* __restrict__ Bp,
                    const float* __restrict__ Tprev, float* __restrict__ Tout,
                    short* __restrict__ BpOut)
{
  const int lane = threadIdx.x & 63;
  const int wid  = threadIdx.x >> 6;
  const int r0 = blockIdx.x << 4;
  const int arow = r0 + (lane & 15);
  const int koff = (lane >> 4) << 3;
  const int ksbase = wid * KSTEPS_W;

  f32x4 acc0 = {0.f, 0.f, 0.f, 0.f};
  f32x4 acc1 = {0.f, 0.f, 0.f, 0.f};

  const float* ap = Af + (size_t)arow * Mdim + ksbase * 32 + koff;
#pragma unroll 8
  for (int ks = 0; ks < KSTEPS_W; ++ks) {
    const int g = ksbase + ks;
    f32x4 a0 = *reinterpret_cast<const f32x4*>(ap);
    f32x4 a1 = *reinterpret_cast<const f32x4*>(ap + 4);
    short8v av;
#pragma unroll
    for (int j = 0; j < 4; ++j) av[j] = bf16c(a0[j]);
#pragma unroll
    for (int j = 0; j < 4; ++j) av[4 + j] = bf16c(a1[j]);
    short8v b0 = Bp[(g << 1) * 64 + lane];
    short8v b1 = Bp[((g << 1) + 1) * 64 + lane];
    acc0 = __builtin_amdgcn_mfma_f32_16x16x32_bf16(av, b0, acc0, 0, 0, 0);
    acc1 = __builtin_amdgcn_mfma_f32_16x16x32_bf16(av, b1, acc1, 0, 0, 0);
    ap += 32;
  }

  __shared__ float Cl[NWAVES][16][32];
  __shared__ float Cred[16][32];
  {
    const int crow = (lane >> 4) << 2;
    const int ccol = lane & 15;
#pragma unroll
    for (int q = 0; q < 4; ++q) {
      Cl[wid][crow + q][ccol] = acc0[q];
      Cl[wid][crow + q][16 + ccol] = acc1[q];
    }
  }
  __syncthreads();
  {
    const int t = threadIdx.x;
    const int row = t >> 5, col = t & 31;
    float v = Cl[0][row][col] + Cl[1][row][col] + Cl[2][row][col] + Cl[3][row][col]
            + Cl[4][row][col] + Cl[5][row][col] + Cl[6][row][col] + Cl[7][row][col];
    if constexpr (HASPREV) {
      v = 2.f * v - Tprev[(size_t)r0 * 32 + t];
    }
    Tout[(size_t)r0 * 32 + t] = v;
    Cred[row][col] = v;
  }
  __syncthreads();
  if (threadIdx.x < 64) {
    const int t = threadIdx.x;
    const int ksOut = r0 >> 5;
    const int sub = (r0 >> 4) & 1;
    const int h = t >> 5;
    const int lp = (t & 31) + sub * 32;
    const int col = h * 16 + (lp & 15);
    const int lrbase = (lp & 16) ? 8 : 0;
    short8v v;
#pragma unroll
    for (int j = 0; j < 8; ++j) v[j] = bf16c(Cred[lrbase + j][col]);
    reinterpret_cast<short8v*>(BpOut)[(ksOut << 1 | h) * 64 + lp] = v;
  }
}

// y[n][o] = sum_k sum_i Xk[n][i] * W[i][o][k],  W: [32][32][7] f32
__global__ __launch_bounds__(256)
void combine(const float* __restrict__ x,
             const float* __restrict__ T1l, const float* __restrict__ T2l,
             const float* __restrict__ T3l, const float* __restrict__ T1u,
             const float* __restrict__ T2u, const float* __restrict__ T3u,
             const float* __restrict__ W, float* __restrict__ y)
{
  __shared__ float Wl[7168];
  for (int i = threadIdx.x; i < 7168; i += 256) Wl[i] = W[i];
  __syncthreads();
  int t = blockIdx.x * 256 + threadIdx.x;
  int n = t >> 5, o = t & 31;
  const float* Xs[7] = {x, T1l, T2l, T3l, T1u, T2u, T3u};
  float sum = 0.f;
#pragma unroll
  for (int k = 0; k < 7; ++k) {
    const f32x4* Xr = reinterpret_cast<const f32x4*>(Xs[k] + (size_t)n * 32);
#pragma unroll
    for (int i4 = 0; i4 < 8; ++i4) {
      f32x4 xv = Xr[i4];
#pragma unroll
      for (int j = 0; j < 4; ++j)
        sum += xv[j] * Wl[(i4 * 4 + j) * 224 + o * 7 + k];
    }
  }
  y[t] = sum;
}

extern "C" void kernel_launch(void* const* d_in, const int* in_sizes, int n_in,
                              void* d_out, int out_size, void* d_ws, size_t ws_size,
                              hipStream_t stream)
{
  const float* x  = (const float*)d_in[0];
  const float* Ll = (const float*)d_in[1];
  const float* Lu = (const float*)d_in[2];
  const float* W  = (const float*)d_in[3];
  float* y = (float*)d_out;

  char* ws = (char*)d_ws;
  size_t off = 0;
  auto alloc = [&](size_t bytes) -> void* {
    void* p = ws + off; off += (bytes + 255) & ~(size_t)255; return p;
  };
  short* Bx  = (short*)alloc(512 * 1024);
  short* Bp0 = (short*)alloc(512 * 1024);
  short* Bp1 = (short*)alloc(512 * 1024);
  float* T1l = (float*)alloc(1u << 20);
  float* T2l = (float*)alloc(1u << 20);
  float* T3l = (float*)alloc(1u << 20);
  float* T1u = (float*)alloc(1u << 20);
  float* T2u = (float*)alloc(1u << 20);
  float* T3u = (float*)alloc(1u << 20);

  const size_t lbytes = (size_t)Mdim * Mdim * sizeof(short);
  bool useBF = (ws_size >= off + 2 * lbytes);
  short* Llb = nullptr; short* Lub = nullptr;
  if (useBF) { Llb = (short*)alloc(lbytes); Lub = (short*)alloc(lbytes); }

  repack_x<<<128, 256, 0, stream>>>(x, Bx);

  const int n8 = Mdim * (Mdim / 8);   // 8,388,608 short8v groups per matrix

  if (useBF) {
    // Chain l: convert then 3 bf16 stages while Llb (134 MB) is L3-resident.
    convert_bf16<<<2048, 256, 0, stream>>>(Ll, Llb, n8);
    gemm_bf16_stage<0><<<512,512,0,stream>>>(Llb, Bx,  nullptr, T1l, Bp0);
    gemm_bf16_stage<1><<<512,512,0,stream>>>(Llb, Bp0, x,       T2l, Bp1);
    gemm_bf16_stage<1><<<512,512,0,stream>>>(Llb, Bp1, T1l,     T3l, Bp0);
    // Chain u
    convert_bf16<<<2048, 256, 0, stream>>>(Lu, Lub, n8);
    gemm_bf16_stage<0><<<512,512,0,stream>>>(Lub, Bx,  nullptr, T1u, Bp0);
    gemm_bf16_stage<1><<<512,512,0,stream>>>(Lub, Bp0, x,       T2u, Bp1);
    gemm_bf16_stage<1><<<512,512,0,stream>>>(Lub, Bp1, T1u,     T3u, Bp0);
  } else {
    gemm_f32_stage<0><<<512,512,0,stream>>>(Ll, (const short8v*)Bx,  nullptr, T1l, Bp0);
    gemm_f32_stage<1><<<512,512,0,stream>>>(Ll, (const short8v*)Bp0, x,       T2l, Bp1);
    gemm_f32_stage<1><<<512,512,0,stream>>>(Ll, (const short8v*)Bp1, T1l,     T3l, Bp0);
    gemm_f32_stage<0><<<512,512,0,stream>>>(Lu, (const short8v*)Bx,  nullptr, T1u, Bp0);
    gemm_f32_stage<1><<<512,512,0,stream>>>(Lu, (const short8v*)Bp0, x,       T2u, Bp1);
    gemm_f32_stage<1><<<512,512,0,stream>>>(Lu, (const short8v*)Bp1, T1u,     T3u, Bp0);
  }

  combine<<<1024, 256, 0, stream>>>(x, T1l, T2l, T3l, T1u, T2u, T3u, W, y);
}

// Round 8
// 307.997 us; speedup vs baseline: 1.2640x; 1.1110x over previous
//
#include <hip/hip_runtime.h>
#include <hip/hip_bf16.h>
#include <stdint.h>

#define Mdim 8192
#define KSTEPS 256        // 8192 / 32

typedef __attribute__((ext_vector_type(8))) short short8v;  // 8 bf16
typedef __attribute__((ext_vector_type(4))) float f32x4;

// f32 -> bf16 RNE via standard cast (compiler emits v_cvt_pk_bf16_f32)
static __device__ __forceinline__ short bf16c(float f) {
  __hip_bfloat16 h = __float2bfloat16(f);
  union { __hip_bfloat16 h; short s; } c; c.h = h;
  return c.s;
}

// Convert f32 L (row-major) into bf16 FRAGMENT-LINEAR layout:
//   dst record (tile*256+ks), lane ln, elem j =
//     bf16( L[tile*16 + (ln&15)][ks*32 + (ln>>4)*8 + j] )
// so the GEMM reads each lane's fragment as ONE contiguous 16 B
// (coalesced 1 KB/wave/instruction). f32 reads here are coalesced and
// nontemporal (don't thrash L3); bf16 writes are coalesced.
__global__ __launch_bounds__(256)
void convert_repack(const float* __restrict__ src, short* __restrict__ dst)
{
  __shared__ __align__(16) short Lb[16][1032];   // +8 pad keeps 16B rows, breaks conflicts
  const int tile = blockIdx.x >> 3;       // 0..511 (16-row tile)
  const int slab = blockIdx.x & 7;        // 32 k-steps = 1024 elements
  const int t = threadIdx.x;

  // phase 1: 16 rows x 1024 f32 -> bf16 in LDS (coalesced 4 KB per iteration)
  for (int i = 0; i < 16; ++i) {
    const f32x4* p = reinterpret_cast<const f32x4*>(
        src + ((size_t)tile * 16 + i) * Mdim + slab * 1024) + t;
    f32x4 a = __builtin_nontemporal_load(p);
    short* q = &Lb[i][t * 4];
    q[0] = bf16c(a[0]); q[1] = bf16c(a[1]); q[2] = bf16c(a[2]); q[3] = bf16c(a[3]);
  }
  __syncthreads();

  // phase 2: 2048 record-lanes (32 k-steps x 64 lanes), coalesced 16B writes
  for (int it = 0; it < 8; ++it) {
    const int c = it * 256 + t;
    const int ksl = c >> 6, ln = c & 63;
    short8v v = *reinterpret_cast<const short8v*>(
        &Lb[ln & 15][ksl * 32 + ((ln >> 4) << 3)]);
    reinterpret_cast<short8v*>(dst)[(size_t)(tile * 256 + slab * 32 + ksl) * 64 + ln] = v;
  }
}

// Repack x (f32 [8192][32]) into MFMA B-fragment layout:
// Bp[((ks*2 + h)*64 + lane)*8 + j] = bf16( B[ks*32 + (lane>>4)*8 + j][h*16 + (lane&15)] )
__global__ __launch_bounds__(256)
void repack_x(const float* __restrict__ x, short* __restrict__ Bp)
{
  int t = blockIdx.x * 256 + threadIdx.x;       // 32768 threads total
  int l = t & 63, h = (t >> 6) & 1, ks = t >> 7;
  int col = h * 16 + (l & 15);
  int kbase = ks * 32 + ((l >> 4) << 3);
  short8v v;
#pragma unroll
  for (int j = 0; j < 8; ++j) v[j] = bf16c(x[(size_t)(kbase + j) * 32 + col]);
  reinterpret_cast<short8v*>(Bp)[t] = v;
}

// Chebyshev GEMM stage, both chains fused:
//   blocks 0..511 -> chain l, 512..1023 -> chain u; block = one 16-row tile.
// Tout = (A @ B) [HASPREV=0]  or  2*(A @ B) - Tprev [HASPREV=1]
// A: bf16 FRAGMENT-LINEAR (convert_repack) -> every lane's fragment is one
// contiguous 16 B; plain register loads, compiler-scheduled (no LDS staging,
// no DMA, no inline asm -> no cross-queue races; round-5 proven structure).
// 512 thr = 8 waves, K-split 8 x 1024 (32 k-steps/wave), LDS reduction.
template<int HASPREV>
__global__ __launch_bounds__(512)
void gemm_pair(const short* __restrict__ AsL, const short* __restrict__ AsU,
               const short* __restrict__ BpsL, const short* __restrict__ BpsU,
               const float* __restrict__ TprevL, const float* __restrict__ TprevU,
               float* __restrict__ ToutL, float* __restrict__ ToutU,
               short* __restrict__ BpOutL, short* __restrict__ BpOutU)
{
  const int chain = blockIdx.x >> 9;
  const short* As    = chain ? AsU : AsL;
  const short* Bps   = chain ? BpsU : BpsL;
  const float* Tprev = chain ? TprevU : TprevL;
  float* Tout  = chain ? ToutU : ToutL;
  short* BpOut = chain ? BpOutU : BpOutL;

  const int bTile = blockIdx.x & 511;
  const int lane = threadIdx.x & 63;
  const int wid  = threadIdx.x >> 6;        // wave 0..7 -> k-chunk of 32 steps
  const int r0 = bTile << 4;
  const int ksbase = wid * 32;

  // fragment-linear cursors: record stride = 64 short8v (1 KB)
  const short8v* aF = reinterpret_cast<const short8v*>(As)
                      + ((size_t)bTile * 256 + ksbase) * 64 + lane;
  const short8v* bF = reinterpret_cast<const short8v*>(Bps)
                      + (size_t)ksbase * 128 + lane;

  f32x4 acc0 = {0.f, 0.f, 0.f, 0.f};        // cols 0..15
  f32x4 acc1 = {0.f, 0.f, 0.f, 0.f};        // cols 16..31

#pragma unroll 8
  for (int ks = 0; ks < 32; ++ks) {
    short8v av = aF[ks * 64];
    short8v b0 = bF[ks * 128];
    short8v b1 = bF[ks * 128 + 64];
    acc0 = __builtin_amdgcn_mfma_f32_16x16x32_bf16(av, b0, acc0, 0, 0, 0);
    acc1 = __builtin_amdgcn_mfma_f32_16x16x32_bf16(av, b1, acc1, 0, 0, 0);
  }

  // ---- per-wave partials -> LDS ----
  // C/D layout: col = lane&15, row = (lane>>4)*4 + reg  (m89-verified)
  __shared__ float Cl[8][16][32];   // 16 KB partials
  __shared__ float Cred[16][32];    // 2 KB reduced tile
  {
    const int crow = (lane >> 4) << 2;
    const int ccol = lane & 15;
#pragma unroll
    for (int q = 0; q < 4; ++q) {
      Cl[wid][crow + q][ccol] = acc0[q];
      Cl[wid][crow + q][16 + ccol] = acc1[q];
    }
  }
  __syncthreads();

  // ---- reduce 8 partials + Chebyshev recurrence + Tout write ----
  {
    const int t = threadIdx.x;
    const int row = t >> 5, col = t & 31;
    float v = Cl[0][row][col] + Cl[1][row][col] + Cl[2][row][col] + Cl[3][row][col]
            + Cl[4][row][col] + Cl[5][row][col] + Cl[6][row][col] + Cl[7][row][col];
    if constexpr (HASPREV) {
      v = 2.f * v - Tprev[(size_t)r0 * 32 + t];
    }
    Tout[(size_t)r0 * 32 + t] = v;
    Cred[row][col] = v;
  }
  __syncthreads();

  // ---- BpOut fragment write: 64 short8v entries for this 16-row tile ----
  if (threadIdx.x < 64) {
    const int t = threadIdx.x;
    const int ksOut = r0 >> 5;
    const int sub = (r0 >> 4) & 1;          // which half of the 32-row group
    const int h = t >> 5;                   // column half 0/1
    const int lp = (t & 31) + sub * 32;     // fragment lane we produce
    const int col = h * 16 + (lp & 15);
    const int lrbase = (lp & 16) ? 8 : 0;   // local row base within our 16 rows
    short8v v;
#pragma unroll
    for (int j = 0; j < 8; ++j) v[j] = bf16c(Cred[lrbase + j][col]);
    reinterpret_cast<short8v*>(BpOut)[(ksOut << 1 | h) * 64 + lp] = v;
  }
}

// Fallback f32-A stage (only if workspace lacks room for bf16 copies).
template<int HASPREV>
__global__ __launch_bounds__(512)
void gemm_f32_stage(const float* __restrict__ Af, const short8v* __restrict__ Bp,
                    const float* __restrict__ Tprev, float* __restrict__ Tout,
                    short* __restrict__ BpOut)
{
  const int lane = threadIdx.x & 63;
  const int wid  = threadIdx.x >> 6;
  const int r0 = blockIdx.x << 4;
  const int arow = r0 + (lane & 15);
  const int koff = (lane >> 4) << 3;
  const int ksbase = wid * 32;

  f32x4 acc0 = {0.f, 0.f, 0.f, 0.f};
  f32x4 acc1 = {0.f, 0.f, 0.f, 0.f};

  const float* ap = Af + (size_t)arow * Mdim + ksbase * 32 + koff;
#pragma unroll 8
  for (int ks = 0; ks < 32; ++ks) {
    const int g = ksbase + ks;
    f32x4 a0 = *reinterpret_cast<const f32x4*>(ap);
    f32x4 a1 = *reinterpret_cast<const f32x4*>(ap + 4);
    short8v av;
#pragma unroll
    for (int j = 0; j < 4; ++j) av[j] = bf16c(a0[j]);
#pragma unroll
    for (int j = 0; j < 4; ++j) av[4 + j] = bf16c(a1[j]);
    short8v b0 = Bp[(g << 1) * 64 + lane];
    short8v b1 = Bp[((g << 1) + 1) * 64 + lane];
    acc0 = __builtin_amdgcn_mfma_f32_16x16x32_bf16(av, b0, acc0, 0, 0, 0);
    acc1 = __builtin_amdgcn_mfma_f32_16x16x32_bf16(av, b1, acc1, 0, 0, 0);
    ap += 32;
  }

  __shared__ float Cl[8][16][32];
  __shared__ float Cred[16][32];
  {
    const int crow = (lane >> 4) << 2;
    const int ccol = lane & 15;
#pragma unroll
    for (int q = 0; q < 4; ++q) {
      Cl[wid][crow + q][ccol] = acc0[q];
      Cl[wid][crow + q][16 + ccol] = acc1[q];
    }
  }
  __syncthreads();
  {
    const int t = threadIdx.x;
    const int row = t >> 5, col = t & 31;
    float v = Cl[0][row][col] + Cl[1][row][col] + Cl[2][row][col] + Cl[3][row][col]
            + Cl[4][row][col] + Cl[5][row][col] + Cl[6][row][col] + Cl[7][row][col];
    if constexpr (HASPREV) {
      v = 2.f * v - Tprev[(size_t)r0 * 32 + t];
    }
    Tout[(size_t)r0 * 32 + t] = v;
    Cred[row][col] = v;
  }
  __syncthreads();
  if (threadIdx.x < 64) {
    const int t = threadIdx.x;
    const int ksOut = r0 >> 5;
    const int sub = (r0 >> 4) & 1;
    const int h = t >> 5;
    const int lp = (t & 31) + sub * 32;
    const int col = h * 16 + (lp & 15);
    const int lrbase = (lp & 16) ? 8 : 0;
    short8v v;
#pragma unroll
    for (int j = 0; j < 8; ++j) v[j] = bf16c(Cred[lrbase + j][col]);
    reinterpret_cast<short8v*>(BpOut)[(ksOut << 1 | h) * 64 + lp] = v;
  }
}

// y[n][o] = sum_k sum_i Xk[n][i] * W[i][o][k],  W: [32][32][7] f32
__global__ __launch_bounds__(256)
void combine(const float* __restrict__ x,
             const float* __restrict__ T1l, const float* __restrict__ T2l,
             const float* __restrict__ T3l, const float* __restrict__ T1u,
             const float* __restrict__ T2u, const float* __restrict__ T3u,
             const float* __restrict__ W, float* __restrict__ y)
{
  __shared__ float Wl[7168];
  for (int i = threadIdx.x; i < 7168; i += 256) Wl[i] = W[i];
  __syncthreads();
  int t = blockIdx.x * 256 + threadIdx.x;
  int n = t >> 5, o = t & 31;
  const float* Xs[7] = {x, T1l, T2l, T3l, T1u, T2u, T3u};
  float sum = 0.f;
#pragma unroll
  for (int k = 0; k < 7; ++k) {
    const f32x4* Xr = reinterpret_cast<const f32x4*>(Xs[k] + (size_t)n * 32);
#pragma unroll
    for (int i4 = 0; i4 < 8; ++i4) {
      f32x4 xv = Xr[i4];
#pragma unroll
      for (int j = 0; j < 4; ++j)
        sum += xv[j] * Wl[(i4 * 4 + j) * 224 + o * 7 + k];
    }
  }
  y[t] = sum;
}

extern "C" void kernel_launch(void* const* d_in, const int* in_sizes, int n_in,
                              void* d_out, int out_size, void* d_ws, size_t ws_size,
                              hipStream_t stream)
{
  const float* x  = (const float*)d_in[0];
  const float* Ll = (const float*)d_in[1];
  const float* Lu = (const float*)d_in[2];
  const float* W  = (const float*)d_in[3];
  float* y = (float*)d_out;

  char* ws = (char*)d_ws;
  size_t off = 0;
  auto alloc = [&](size_t bytes) -> void* {
    void* p = ws + off; off += (bytes + 255) & ~(size_t)255; return p;
  };
  short* Bx  = (short*)alloc(512 * 1024);
  short* Bl1 = (short*)alloc(512 * 1024);
  short* Bl2 = (short*)alloc(512 * 1024);
  short* Bu1 = (short*)alloc(512 * 1024);
  short* Bu2 = (short*)alloc(512 * 1024);
  float* T1l = (float*)alloc(1u << 20);
  float* T2l = (float*)alloc(1u << 20);
  float* T3l = (float*)alloc(1u << 20);
  float* T1u = (float*)alloc(1u << 20);
  float* T2u = (float*)alloc(1u << 20);
  float* T3u = (float*)alloc(1u << 20);

  const size_t lbytes = (size_t)Mdim * Mdim * sizeof(short);
  bool useBF = (ws_size >= off + 2 * lbytes);
  short* Llb = nullptr; short* Lub = nullptr;
  if (useBF) { Llb = (short*)alloc(lbytes); Lub = (short*)alloc(lbytes); }

  repack_x<<<128, 256, 0, stream>>>(x, Bx);

  if (useBF) {
    convert_repack<<<4096, 256, 0, stream>>>(Ll, Llb);
    convert_repack<<<4096, 256, 0, stream>>>(Lu, Lub);
    gemm_pair<0><<<1024,512,0,stream>>>(Llb, Lub, Bx,  Bx,  nullptr, nullptr, T1l, T1u, Bl1, Bu1);
    gemm_pair<1><<<1024,512,0,stream>>>(Llb, Lub, Bl1, Bu1, x,       x,       T2l, T2u, Bl2, Bu2);
    gemm_pair<1><<<1024,512,0,stream>>>(Llb, Lub, Bl2, Bu2, T1l,     T1u,     T3l, T3u, Bl1, Bu1);
  } else {
    gemm_f32_stage<0><<<512,512,0,stream>>>(Ll, (const short8v*)Bx,  nullptr, T1l, Bl1);
    gemm_f32_stage<1><<<512,512,0,stream>>>(Ll, (const short8v*)Bl1, x,       T2l, Bl2);
    gemm_f32_stage<1><<<512,512,0,stream>>>(Ll, (const short8v*)Bl2, T1l,     T3l, Bl1);
    gemm_f32_stage<0><<<512,512,0,stream>>>(Lu, (const short8v*)Bx,  nullptr, T1u, Bu1);
    gemm_f32_stage<1><<<512,512,0,stream>>>(Lu, (const short8v*)Bu1, x,       T2u, Bu2);
    gemm_f32_stage<1><<<512,512,0,stream>>>(Lu, (const short8v*)Bu2, T1u,     T3u, Bu1);
  }

  combine<<<1024, 256, 0, stream>>>(x, T1l, T2l, T3l, T1u, T2u, T3u, W, y);
}

// Round 9
// 253.227 us; speedup vs baseline: 1.5373x; 1.2163x over previous
//
#include <hip/hip_runtime.h>
#include <hip/hip_bf16.h>
#include <stdint.h>

#define Mdim 8192
#define KSTEPS 256        // 8192 / 32

typedef __attribute__((ext_vector_type(8))) short short8v;  // 8 bf16
typedef __attribute__((ext_vector_type(4))) float f32x4;
typedef __attribute__((ext_vector_type(2))) float f32x2;

// f32 -> bf16 RNE via standard cast (compiler emits v_cvt_pk_bf16_f32)
static __device__ __forceinline__ short bf16c(float f) {
  __hip_bfloat16 h = __float2bfloat16(f);
  union { __hip_bfloat16 h; short s; } c; c.h = h;
  return c.s;
}

// Repack x (f32 [8192][32]) into MFMA B-fragment layout:
// Bp[((ks*2 + h)*64 + lane)*8 + j] = bf16( B[ks*32 + (lane>>4)*8 + j][h*16 + (lane&15)] )
__global__ __launch_bounds__(256)
void repack_x(const float* __restrict__ x, short* __restrict__ Bp)
{
  int t = blockIdx.x * 256 + threadIdx.x;       // 32768 threads total
  int l = t & 63, h = (t >> 6) & 1, ks = t >> 7;
  int col = h * 16 + (l & 15);
  int kbase = ks * 32 + ((l >> 4) << 3);
  short8v v;
#pragma unroll
  for (int j = 0; j < 8; ++j) v[j] = bf16c(x[(size_t)(kbase + j) * 32 + col]);
  reinterpret_cast<short8v*>(Bp)[t] = v;
}

// Convert f32 L -> bf16 FRAGMENT-LINEAR layout AND accumulate this slab's
// partial of T1 = L @ x via MFMA (A-fragments are already in LDS; B = Bx).
// Block = (tile, slab): 16 rows x 1024 cols. 256 thr = 4 waves.
// Partial out: Pt1[(tile*8+slab)][512] f32 (16x32 tile, flat row*32+col).
__global__ __launch_bounds__(256)
void convert_t1(const float* __restrict__ src, const short* __restrict__ Bx,
                short* __restrict__ dst, float* __restrict__ Pt1)
{
  __shared__ __align__(16) char sh[16 * 1032 * 2];   // 33 KB: Lb, then reused as Clf
  short (*Lb)[1032] = reinterpret_cast<short (*)[1032]>(sh);

  const int tile = blockIdx.x >> 3;       // 0..511 (16-row tile)
  const int slab = blockIdx.x & 7;        // 32 k-steps = 1024 columns
  const int t = threadIdx.x;
  const int lane = t & 63;
  const int wid  = t >> 6;

  // phase 1: 16 rows x 1024 f32 -> bf16 in LDS (coalesced, nontemporal)
  for (int i = 0; i < 16; ++i) {
    const f32x4* p = reinterpret_cast<const f32x4*>(
        src + ((size_t)tile * 16 + i) * Mdim + slab * 1024) + t;
    f32x4 a = __builtin_nontemporal_load(p);
    short* q = &Lb[i][t * 4];
    q[0] = bf16c(a[0]); q[1] = bf16c(a[1]); q[2] = bf16c(a[2]); q[3] = bf16c(a[3]);
  }
  __syncthreads();

  // phase 2: write fragment-linear records + MFMA partial T1.
  // iteration it: wave wid handles record ksl = it*4 + wid (all 64 lanes).
  const short8v* bx8 = reinterpret_cast<const short8v*>(Bx);
  f32x4 acc0 = {0.f, 0.f, 0.f, 0.f};
  f32x4 acc1 = {0.f, 0.f, 0.f, 0.f};
#pragma unroll
  for (int it = 0; it < 8; ++it) {
    const int ksl = it * 4 + wid;
    short8v av = *reinterpret_cast<const short8v*>(
        &Lb[lane & 15][ksl * 32 + ((lane >> 4) << 3)]);
    reinterpret_cast<short8v*>(dst)[(size_t)(tile * 256 + slab * 32 + ksl) * 64 + lane] = av;
    const int gks = slab * 32 + ksl;
    short8v b0 = bx8[(size_t)(gks << 1) * 64 + lane];
    short8v b1 = bx8[(size_t)((gks << 1) + 1) * 64 + lane];
    acc0 = __builtin_amdgcn_mfma_f32_16x16x32_bf16(av, b0, acc0, 0, 0, 0);
    acc1 = __builtin_amdgcn_mfma_f32_16x16x32_bf16(av, b1, acc1, 0, 0, 0);
  }

  // cross-wave reduce of the 4 partials (reuse LDS after barrier)
  __syncthreads();
  float* Clf = reinterpret_cast<float*>(sh);   // [4][16][32] = 8 KB
  {
    // C/D layout: col = lane&15, row = (lane>>4)*4 + reg  (m89-verified)
    const int crow = (lane >> 4) << 2;
    const int ccol = lane & 15;
#pragma unroll
    for (int q = 0; q < 4; ++q) {
      Clf[((wid * 16) + crow + q) * 32 + ccol] = acc0[q];
      Clf[((wid * 16) + crow + q) * 32 + 16 + ccol] = acc1[q];
    }
  }
  __syncthreads();
  {
    const int e = t * 2;
    const int row = e >> 5, col = e & 31;
    float v0 = Clf[row * 32 + col] + Clf[(16 + row) * 32 + col]
             + Clf[(32 + row) * 32 + col] + Clf[(48 + row) * 32 + col];
    float v1 = Clf[row * 32 + col + 1] + Clf[(16 + row) * 32 + col + 1]
             + Clf[(32 + row) * 32 + col + 1] + Clf[(48 + row) * 32 + col + 1];
    f32x2 o; o[0] = v0; o[1] = v1;
    *reinterpret_cast<f32x2*>(Pt1 + (size_t)(tile * 8 + slab) * 512 + e) = o;
  }
}

// Sum the 8 slab-partials -> T1 (f32) + T1 B-fragments.
__global__ __launch_bounds__(256)
void reduce_t1(const float* __restrict__ Pt1, float* __restrict__ Tout,
               short* __restrict__ BpOut)
{
  __shared__ float Cred[16][32];
  const int tile = blockIdx.x;
  const int t = threadIdx.x;
  const int e = t * 2;
  float s0 = 0.f, s1 = 0.f;
#pragma unroll
  for (int s = 0; s < 8; ++s) {
    f32x2 v = *reinterpret_cast<const f32x2*>(Pt1 + (size_t)(tile * 8 + s) * 512 + e);
    s0 += v[0]; s1 += v[1];
  }
  f32x2 o; o[0] = s0; o[1] = s1;
  *reinterpret_cast<f32x2*>(Tout + (size_t)tile * 512 + e) = o;
  Cred[e >> 5][e & 31] = s0;
  Cred[e >> 5][(e & 31) + 1] = s1;
  __syncthreads();
  if (t < 64) {
    const int r0 = tile << 4;
    const int ksOut = r0 >> 5;
    const int sub = (r0 >> 4) & 1;
    const int h = t >> 5;
    const int lp = (t & 31) + sub * 32;
    const int col = h * 16 + (lp & 15);
    const int lrbase = (lp & 16) ? 8 : 0;
    short8v v;
#pragma unroll
    for (int j = 0; j < 8; ++j) v[j] = bf16c(Cred[lrbase + j][col]);
    reinterpret_cast<short8v*>(BpOut)[(ksOut << 1 | h) * 64 + lp] = v;
  }
}

// Chebyshev GEMM stage, single chain: Tout = 2*(A @ B) - Tprev.
// A: bf16 FRAGMENT-LINEAR; B: fragment-packed bf16. 512 blocks x 512 thr
// (8 waves, K-split 8 x 1024). Round-8 proven structure.
template<int HASPREV>
__global__ __launch_bounds__(512)
void gemm_stage(const short* __restrict__ As, const short* __restrict__ Bps,
                const float* __restrict__ Tprev, float* __restrict__ Tout,
                short* __restrict__ BpOut)
{
  const int bTile = blockIdx.x;
  const int lane = threadIdx.x & 63;
  const int wid  = threadIdx.x >> 6;        // wave 0..7 -> k-chunk of 32 steps
  const int r0 = bTile << 4;
  const int ksbase = wid * 32;

  const short8v* aF = reinterpret_cast<const short8v*>(As)
                      + ((size_t)bTile * 256 + ksbase) * 64 + lane;
  const short8v* bF = reinterpret_cast<const short8v*>(Bps)
                      + (size_t)ksbase * 128 + lane;

  f32x4 acc0 = {0.f, 0.f, 0.f, 0.f};        // cols 0..15
  f32x4 acc1 = {0.f, 0.f, 0.f, 0.f};        // cols 16..31

#pragma unroll 8
  for (int ks = 0; ks < 32; ++ks) {
    short8v av = aF[ks * 64];
    short8v b0 = bF[ks * 128];
    short8v b1 = bF[ks * 128 + 64];
    acc0 = __builtin_amdgcn_mfma_f32_16x16x32_bf16(av, b0, acc0, 0, 0, 0);
    acc1 = __builtin_amdgcn_mfma_f32_16x16x32_bf16(av, b1, acc1, 0, 0, 0);
  }

  __shared__ float Cl[8][16][32];   // 16 KB partials
  __shared__ float Cred[16][32];    // 2 KB reduced tile
  {
    const int crow = (lane >> 4) << 2;
    const int ccol = lane & 15;
#pragma unroll
    for (int q = 0; q < 4; ++q) {
      Cl[wid][crow + q][ccol] = acc0[q];
      Cl[wid][crow + q][16 + ccol] = acc1[q];
    }
  }
  __syncthreads();
  {
    const int t = threadIdx.x;
    const int row = t >> 5, col = t & 31;
    float v = Cl[0][row][col] + Cl[1][row][col] + Cl[2][row][col] + Cl[3][row][col]
            + Cl[4][row][col] + Cl[5][row][col] + Cl[6][row][col] + Cl[7][row][col];
    if constexpr (HASPREV) {
      v = 2.f * v - Tprev[(size_t)r0 * 32 + t];
    }
    Tout[(size_t)r0 * 32 + t] = v;
    Cred[row][col] = v;
  }
  __syncthreads();
  if (threadIdx.x < 64) {
    const int t = threadIdx.x;
    const int ksOut = r0 >> 5;
    const int sub = (r0 >> 4) & 1;
    const int h = t >> 5;
    const int lp = (t & 31) + sub * 32;
    const int col = h * 16 + (lp & 15);
    const int lrbase = (lp & 16) ? 8 : 0;
    short8v v;
#pragma unroll
    for (int j = 0; j < 8; ++j) v[j] = bf16c(Cred[lrbase + j][col]);
    reinterpret_cast<short8v*>(BpOut)[(ksOut << 1 | h) * 64 + lp] = v;
  }
}

// Fallback f32-A stage (only if workspace lacks room for the bf16 copy).
template<int HASPREV>
__global__ __launch_bounds__(512)
void gemm_f32_stage(const float* __restrict__ Af, const short8v* __restrict__ Bp,
                    const float* __restrict__ Tprev, float* __restrict__ Tout,
                    short* __restrict__ BpOut)
{
  const int lane = threadIdx.x & 63;
  const int wid  = threadIdx.x >> 6;
  const int r0 = blockIdx.x << 4;
  const int arow = r0 + (lane & 15);
  const int koff = (lane >> 4) << 3;
  const int ksbase = wid * 32;

  f32x4 acc0 = {0.f, 0.f, 0.f, 0.f};
  f32x4 acc1 = {0.f, 0.f, 0.f, 0.f};

  const float* ap = Af + (size_t)arow * Mdim + ksbase * 32 + koff;
#pragma unroll 8
  for (int ks = 0; ks < 32; ++ks) {
    const int g = ksbase + ks;
    f32x4 a0 = *reinterpret_cast<const f32x4*>(ap);
    f32x4 a1 = *reinterpret_cast<const f32x4*>(ap + 4);
    short8v av;
#pragma unroll
    for (int j = 0; j < 4; ++j) av[j] = bf16c(a0[j]);
#pragma unroll
    for (int j = 0; j < 4; ++j) av[4 + j] = bf16c(a1[j]);
    short8v b0 = Bp[(g << 1) * 64 + lane];
    short8v b1 = Bp[((g << 1) + 1) * 64 + lane];
    acc0 = __builtin_amdgcn_mfma_f32_16x16x32_bf16(av, b0, acc0, 0, 0, 0);
    acc1 = __builtin_amdgcn_mfma_f32_16x16x32_bf16(av, b1, acc1, 0, 0, 0);
    ap += 32;
  }

  __shared__ float Cl[8][16][32];
  __shared__ float Cred[16][32];
  {
    const int crow = (lane >> 4) << 2;
    const int ccol = lane & 15;
#pragma unroll
    for (int q = 0; q < 4; ++q) {
      Cl[wid][crow + q][ccol] = acc0[q];
      Cl[wid][crow + q][16 + ccol] = acc1[q];
    }
  }
  __syncthreads();
  {
    const int t = threadIdx.x;
    const int row = t >> 5, col = t & 31;
    float v = Cl[0][row][col] + Cl[1][row][col] + Cl[2][row][col] + Cl[3][row][col]
            + Cl[4][row][col] + Cl[5][row][col] + Cl[6][row][col] + Cl[7][row][col];
    if constexpr (HASPREV) {
      v = 2.f * v - Tprev[(size_t)r0 * 32 + t];
    }
    Tout[(size_t)r0 * 32 + t] = v;
    Cred[row][col] = v;
  }
  __syncthreads();
  if (threadIdx.x < 64) {
    const int t = threadIdx.x;
    const int ksOut = r0 >> 5;
    const int sub = (r0 >> 4) & 1;
    const int h = t >> 5;
    const int lp = (t & 31) + sub * 32;
    const int col = h * 16 + (lp & 15);
    const int lrbase = (lp & 16) ? 8 : 0;
    short8v v;
#pragma unroll
    for (int j = 0; j < 8; ++j) v[j] = bf16c(Cred[lrbase + j][col]);
    reinterpret_cast<short8v*>(BpOut)[(ksOut << 1 | h) * 64 + lp] = v;
  }
}

// y[n][o] = sum_k sum_i Xk[n][i] * W[i][o][k],  W: [32][32][7] f32
__global__ __launch_bounds__(256)
void combine(const float* __restrict__ x,
             const float* __restrict__ T1l, const float* __restrict__ T2l,
             const float* __restrict__ T3l, const float* __restrict__ T1u,
             const float* __restrict__ T2u, const float* __restrict__ T3u,
             const float* __restrict__ W, float* __restrict__ y)
{
  __shared__ float Wl[7168];
  for (int i = threadIdx.x; i < 7168; i += 256) Wl[i] = W[i];
  __syncthreads();
  int t = blockIdx.x * 256 + threadIdx.x;
  int n = t >> 5, o = t & 31;
  const float* Xs[7] = {x, T1l, T2l, T3l, T1u, T2u, T3u};
  float sum = 0.f;
#pragma unroll
  for (int k = 0; k < 7; ++k) {
    const f32x4* Xr = reinterpret_cast<const f32x4*>(Xs[k] + (size_t)n * 32);
#pragma unroll
    for (int i4 = 0; i4 < 8; ++i4) {
      f32x4 xv = Xr[i4];
#pragma unroll
      for (int j = 0; j < 4; ++j)
        sum += xv[j] * Wl[(i4 * 4 + j) * 224 + o * 7 + k];
    }
  }
  y[t] = sum;
}

extern "C" void kernel_launch(void* const* d_in, const int* in_sizes, int n_in,
                              void* d_out, int out_size, void* d_ws, size_t ws_size,
                              hipStream_t stream)
{
  const float* x  = (const float*)d_in[0];
  const float* Ll = (const float*)d_in[1];
  const float* Lu = (const float*)d_in[2];
  const float* W  = (const float*)d_in[3];
  float* y = (float*)d_out;

  char* ws = (char*)d_ws;
  size_t off = 0;
  auto alloc = [&](size_t bytes) -> void* {
    void* p = ws + off; off += (bytes + 255) & ~(size_t)255; return p;
  };
  short* Bx = (short*)alloc(512 * 1024);
  short* B1 = (short*)alloc(512 * 1024);
  short* B2 = (short*)alloc(512 * 1024);
  float* T1l = (float*)alloc(1u << 20);
  float* T2l = (float*)alloc(1u << 20);
  float* T3l = (float*)alloc(1u << 20);
  float* T1u = (float*)alloc(1u << 20);
  float* T2u = (float*)alloc(1u << 20);
  float* T3u = (float*)alloc(1u << 20);
  float* Pt1 = (float*)alloc((size_t)512 * 8 * 512 * 4);   // 8 MB partials

  const size_t lbytes = (size_t)Mdim * Mdim * sizeof(short);
  bool useBF = (ws_size >= off + lbytes);
  short* Lab = nullptr;                     // ONE shared bf16 A buffer (both chains)
  if (useBF) Lab = (short*)alloc(lbytes);

  repack_x<<<128, 256, 0, stream>>>(x, Bx);

  if (useBF) {
    // ---- chain l (Lab stays L3-resident through its 3 consumers) ----
    convert_t1<<<4096, 256, 0, stream>>>(Ll, Bx, Lab, Pt1);
    reduce_t1<<<512, 256, 0, stream>>>(Pt1, T1l, B1);
    gemm_stage<1><<<512, 512, 0, stream>>>(Lab, B1, x,   T2l, B2);
    gemm_stage<1><<<512, 512, 0, stream>>>(Lab, B2, T1l, T3l, B1);
    // ---- chain u (reuse Lab: in-cache overwrite, no extra writeback) ----
    convert_t1<<<4096, 256, 0, stream>>>(Lu, Bx, Lab, Pt1);
    reduce_t1<<<512, 256, 0, stream>>>(Pt1, T1u, B1);
    gemm_stage<1><<<512, 512, 0, stream>>>(Lab, B1, x,   T2u, B2);
    gemm_stage<1><<<512, 512, 0, stream>>>(Lab, B2, T1u, T3u, B1);
  } else {
    gemm_f32_stage<0><<<512,512,0,stream>>>(Ll, (const short8v*)Bx, nullptr, T1l, B1);
    gemm_f32_stage<1><<<512,512,0,stream>>>(Ll, (const short8v*)B1, x,      T2l, B2);
    gemm_f32_stage<1><<<512,512,0,stream>>>(Ll, (const short8v*)B2, T1l,    T3l, B1);
    gemm_f32_stage<0><<<512,512,0,stream>>>(Lu, (const short8v*)Bx, nullptr, T1u, B1);
    gemm_f32_stage<1><<<512,512,0,stream>>>(Lu, (const short8v*)B1, x,      T2u, B2);
    gemm_f32_stage<1><<<512,512,0,stream>>>(Lu, (const short8v*)B2, T1u,    T3u, B1);
  }

  combine<<<1024, 256, 0, stream>>>(x, T1l, T2l, T3l, T1u, T2u, T3u, W, y);
}